// Round 10
// baseline (184.643 us; speedup 1.0000x reference)
//
#include <hip/hip_runtime.h>

#define GAMMA 12.0f
#define DIM 256
#define NROWS 500
#define CW 64                               // halves per chunk slice (128 B rows)
#define NCHUNK 4                            // DIM / CW
#define ROWS_PAD 504                        // region = 504*128 B = 64512 B
#define REGION_HALVES (ROWS_PAD * CW)       // 32256
#define REGION_BYTES (REGION_HALVES * 2)    // 64512
#define STAGE_ITERS (REGION_BYTES / 1024)   // 63 wave-loads of 1024 B per chunk
#define THREADS 1024
#define WAVES 16
#define PASSES 8                            // 1024 triplets / (16 waves * 8 groups)
#define TPB 1024
#define TAB_BYTES ((size_t)2 * NCHUNK * REGION_HALVES * 2)   // 516096

typedef _Float16 h2 __attribute__((ext_vector_type(2)));

static __device__ __forceinline__ unsigned short f2h(float x) {
    _Float16 h = (_Float16)x;
    return __builtin_bit_cast(unsigned short, h);
}

// acc += |h + r - t| over one packed f16 pair, f32 accumulate via v_dot2_f32_f16
static __device__ __forceinline__ float acc_pair(unsigned uh, unsigned ur, unsigned ut, float acc) {
    h2 h = __builtin_bit_cast(h2, uh);
    h2 r = __builtin_bit_cast(h2, ur);
    h2 t = __builtin_bit_cast(h2, ut);
    h2 d = (h + r) - t;                                           // v_pk_add_f16 x2
    unsigned ad = __builtin_bit_cast(unsigned, d) & 0x7FFF7FFFu;  // packed abs
    h2 one = { (_Float16)1.0f, (_Float16)1.0f };
    return __builtin_amdgcn_fdot2(__builtin_bit_cast(h2, ad), one, acc, false);
}

// ---- prep: f16 tables (chunk-major) + packed triplet words ----
// tab16: [table][chunk][ROWS_PAD][CW] halves. packed: h|r<<10|t<<20|oob<<30|inv<<31
__global__ __launch_bounds__(256) void transe_prep(
    const float* __restrict__ node, const float* __restrict__ rel,
    const int* __restrict__ trip,
    unsigned short* __restrict__ tab16, unsigned* __restrict__ packed,
    int B, int packn)
{
    int t = blockIdx.x * 256 + threadIdx.x;
    const int per = NROWS * DIM;                 // 128000
    if (t < 2 * per / 8) {
        int t8 = t * 8;
        int table = t8 >= per;
        int e = t8 - table * per;
        const float* src = table ? rel : node;
        float4 f0 = *(const float4*)(src + e);
        float4 f1 = *(const float4*)(src + e + 4);
        int row = e >> 8;
        int d = e & (DIM - 1);
        int c = d >> 6, w = d & (CW - 1);
        union { unsigned short us[8]; uint4 v; } o;
        o.us[0] = f2h(f0.x); o.us[1] = f2h(f0.y); o.us[2] = f2h(f0.z); o.us[3] = f2h(f0.w);
        o.us[4] = f2h(f1.x); o.us[5] = f2h(f1.y); o.us[6] = f2h(f1.z); o.us[7] = f2h(f1.w);
        *(uint4*)(tab16 + (size_t)(table * NCHUNK + c) * REGION_HALVES + row * CW + w) = o.v;
    }
    if (t < packn) {
        unsigned pk;
        if (t < B) {
            int h = trip[3 * (long)t], r = trip[3 * (long)t + 1], tt = trip[3 * (long)t + 2];
            unsigned oob = ((unsigned)h >= NROWS || (unsigned)r >= NROWS || (unsigned)tt >= NROWS)
                           ? (1u << 30) : 0u;
            unsigned hc = (unsigned)min(max(h, 0), NROWS - 1);
            unsigned rc = (unsigned)min(max(r, 0), NROWS - 1);
            unsigned tc = (unsigned)min(max(tt, 0), NROWS - 1);
            pk = hc | (rc << 10) | (tc << 20) | oob;
        } else pk = 1u << 31;
        packed[t] = pk;
    }
}

// ---- main: R5 math, 2 blocks/CU (8 waves/SIMD) ----
// 8 lanes/triplet, 128 B row-chunks. h,t from the single-buffered node chunk in
// LDS (wave ds_read_b128 = 8 rows x 128 B -> each bank exactly 8 words -> zero
// conflicts). r from the L2-resident global f16 table, 1-deep prefetch. LDS is
// just 64.5 KB -> two independent blocks per CU: one block's compute covers the
// other's restage barriers and r-gather latency.
__global__ __launch_bounds__(THREADS, 8) void transe_main3(
    const unsigned short* __restrict__ tab16,
    const unsigned* __restrict__ packed,
    const int* __restrict__ trip,
    const float* __restrict__ node_f32,
    const float* __restrict__ rel_f32,
    float* __restrict__ out, int B)
{
    __shared__ __align__(16) unsigned short lbuf[REGION_HALVES];   // 64512 B

    const int tid  = threadIdx.x;
    const int wid  = tid >> 6;
    const int lane = tid & 63;
    const int g    = lane >> 3;   // group (triplet) within wave
    const int m    = lane & 7;    // member within group
    const int moff = m * 16;
    const int base = blockIdx.x * TPB;

    const char* srcb = (const char*)tab16;
    char* ldsb = (char*)lbuf;

    // stage node chunk 0 (async global->LDS, wave-uniform dest + lane*16)
    #pragma unroll 1
    for (int i = wid; i < STAGE_ITERS; i += WAVES) {
        __builtin_amdgcn_global_load_lds(
            (const __attribute__((address_space(1))) unsigned int*)
                (srcb + (size_t)i * 1024 + (size_t)lane * 16),
            (__attribute__((address_space(3))) unsigned int*)(ldsb + i * 1024),
            16, 0, 0);
    }

    // my 8 packed triplet words straight from global (8-lane-uniform broadcasts)
    unsigned pidx[PASSES];
    #pragma unroll
    for (int p = 0; p < PASSES; ++p)
        pidx[p] = packed[base + wid * (8 * PASSES) + p * 8 + g];

    float acc[PASSES];
    #pragma unroll
    for (int p = 0; p < PASSES; ++p) acc[p] = 0.f;

    __syncthreads();   // chunk 0 staged

    for (int c = 0; c < NCHUNK; ++c) {
        const char* relc = srcb + (size_t)(NCHUNK + c) * REGION_BYTES;

        uint4 rnext = *(const uint4*)(relc + (((pidx[0] >> 10) & 1023u) << 7) + moff);
        #pragma unroll
        for (int p = 0; p < PASSES; ++p) {
            uint4 rv = rnext;
            if (p + 1 < PASSES)
                rnext = *(const uint4*)(relc + (((pidx[p + 1] >> 10) & 1023u) << 7) + moff);
            unsigned pk = pidx[p];
            uint4 hv = *(const uint4*)(ldsb + ((pk & 1023u) << 7) + moff);
            uint4 tv = *(const uint4*)(ldsb + (((pk >> 20) & 1023u) << 7) + moff);
            float a0 = acc[p], a1 = 0.f;
            a0 = acc_pair(hv.x, rv.x, tv.x, a0);
            a1 = acc_pair(hv.y, rv.y, tv.y, a1);
            a0 = acc_pair(hv.z, rv.z, tv.z, a0);
            a1 = acc_pair(hv.w, rv.w, tv.w, a1);
            acc[p] = a0 + a1;
        }

        if (c + 1 < NCHUNK) {
            __syncthreads();   // all waves done reading chunk c
            const char* cb = srcb + (size_t)(c + 1) * REGION_BYTES;
            #pragma unroll 1
            for (int i = wid; i < STAGE_ITERS; i += WAVES) {
                __builtin_amdgcn_global_load_lds(
                    (const __attribute__((address_space(1))) unsigned int*)
                        (cb + (size_t)i * 1024 + (size_t)lane * 16),
                    (__attribute__((address_space(3))) unsigned int*)(ldsb + i * 1024),
                    16, 0, 0);
            }
            __syncthreads();   // chunk c+1 staged
        }
    }

    // reduce over the 8 members of each group; member 0 writes
    #pragma unroll
    for (int p = 0; p < PASSES; ++p) {
        float a = acc[p];
        a += __shfl_xor(a, 1, 64);
        a += __shfl_xor(a, 2, 64);
        a += __shfl_xor(a, 4, 64);
        if (m == 0) {
            unsigned pk = pidx[p];
            long j = base + wid * (8 * PASSES) + p * 8 + g;
            if (!(pk >> 30)) {
                out[j] = GAMMA - a;
            } else if (!(pk >> 31)) {   // oob index: exact f32 fallback (never hit here)
                int hh = trip[3 * j], rr = trip[3 * j + 1], tt = trip[3 * j + 2];
                float s = 0.f;
                for (int d = 0; d < DIM; ++d)
                    s += fabsf(node_f32[(size_t)hh * DIM + d] + rel_f32[(size_t)rr * DIM + d]
                             - node_f32[(size_t)tt * DIM + d]);
                out[j] = GAMMA - s;
            }
        }
    }
}

// Fallback (only if ws is too small)
__global__ __launch_bounds__(256) void transe_direct(
    const float* __restrict__ node_emb,
    const float* __restrict__ rel_emb,
    const int*   __restrict__ triplets,
    float*       __restrict__ out, int B)
{
    const int wave = blockIdx.x * (blockDim.x >> 6) + (threadIdx.x >> 6);
    const int lane = threadIdx.x & 63;
    if (wave >= B) return;
    const int h_idx = triplets[wave * 3 + 0];
    const int r_idx = triplets[wave * 3 + 1];
    const int t_idx = triplets[wave * 3 + 2];
    const float4 h = ((const float4*)(node_emb + (size_t)h_idx * DIM))[lane];
    const float4 r = ((const float4*)(rel_emb  + (size_t)r_idx * DIM))[lane];
    const float4 t = ((const float4*)(node_emb + (size_t)t_idx * DIM))[lane];
    float s = fabsf(h.x + r.x - t.x) + fabsf(h.y + r.y - t.y)
            + fabsf(h.z + r.z - t.z) + fabsf(h.w + r.w - t.w);
    #pragma unroll
    for (int off = 32; off > 0; off >>= 1) s += __shfl_down(s, off, 64);
    if (lane == 0) out[wave] = GAMMA - s;
}

extern "C" void kernel_launch(void* const* d_in, const int* in_sizes, int n_in,
                              void* d_out, int out_size, void* d_ws, size_t ws_size,
                              hipStream_t stream) {
    const float* node_emb = (const float*)d_in[0];
    const float* rel_emb  = (const float*)d_in[1];
    const int*   triplets = (const int*)d_in[2];
    float*       out      = (float*)d_out;
    const int B = out_size;

    const int grid  = (B + TPB - 1) / TPB;   // 489 blocks -> ~2 per CU
    const int packn = grid * TPB;
    const size_t ws_needed = TAB_BYTES + (size_t)packn * 4;

    if (ws_size < ws_needed) {
        transe_direct<<<(B + 3) / 4, 256, 0, stream>>>(node_emb, rel_emb, triplets, out, B);
        return;
    }

    unsigned short* tab16 = (unsigned short*)d_ws;
    unsigned* packed = (unsigned*)((char*)d_ws + TAB_BYTES);

    const int prep_threads = max(2 * NROWS * DIM / 8, packn);
    transe_prep<<<(prep_threads + 255) / 256, 256, 0, stream>>>(
        node_emb, rel_emb, triplets, tab16, packed, B, packn);

    transe_main3<<<grid, THREADS, 0, stream>>>(
        tab16, packed, triplets, node_emb, rel_emb, out, B);
}

// Round 11
// 61.771 us; speedup vs baseline: 2.9892x; 2.9892x over previous
//
#include <hip/hip_runtime.h>

#define GAMMA 12.0f
#define DIM 256
#define NROWS 500
#define CW 64                               // halves per chunk slice (128 B rows)
#define NCHUNK 4                            // DIM / CW
#define ROWS_PAD 504                        // region = 504*128 B = 64512 B
#define REGION_HALVES (ROWS_PAD * CW)       // 32256
#define REGION_BYTES (REGION_HALVES * 2)    // 64512
#define STAGE_ITERS (REGION_BYTES / 1024)   // 63 wave-loads of 1024 B per chunk
#define THREADS 512                         // 8 waves -> 2 independent blocks/CU
#define WAVES 8
#define PASSES 16                           // 1024 triplets / (8 waves * 8 groups)
#define TPB 1024
#define TAB_BYTES ((size_t)2 * NCHUNK * REGION_HALVES * 2)   // 516096

typedef _Float16 h2 __attribute__((ext_vector_type(2)));

static __device__ __forceinline__ unsigned short f2h(float x) {
    _Float16 h = (_Float16)x;
    return __builtin_bit_cast(unsigned short, h);
}

// acc += |h + r - t| over one packed f16 pair, f32 accumulate via v_dot2_f32_f16
static __device__ __forceinline__ float acc_pair(unsigned uh, unsigned ur, unsigned ut, float acc) {
    h2 h = __builtin_bit_cast(h2, uh);
    h2 r = __builtin_bit_cast(h2, ur);
    h2 t = __builtin_bit_cast(h2, ut);
    h2 d = (h + r) - t;                                           // v_pk_add_f16 x2
    unsigned ad = __builtin_bit_cast(unsigned, d) & 0x7FFF7FFFu;  // packed abs
    h2 one = { (_Float16)1.0f, (_Float16)1.0f };
    return __builtin_amdgcn_fdot2(__builtin_bit_cast(h2, ad), one, acc, false);
}

// ---- prep: f16 tables (chunk-major) + packed triplet words ----
// tab16: [table][chunk][ROWS_PAD][CW] halves. packed: h|r<<10|t<<20|oob<<30|inv<<31
__global__ __launch_bounds__(256) void transe_prep(
    const float* __restrict__ node, const float* __restrict__ rel,
    const int* __restrict__ trip,
    unsigned short* __restrict__ tab16, unsigned* __restrict__ packed,
    int B, int packn)
{
    int t = blockIdx.x * 256 + threadIdx.x;
    const int per = NROWS * DIM;                 // 128000
    if (t < 2 * per / 8) {
        int t8 = t * 8;
        int table = t8 >= per;
        int e = t8 - table * per;
        const float* src = table ? rel : node;
        float4 f0 = *(const float4*)(src + e);
        float4 f1 = *(const float4*)(src + e + 4);
        int row = e >> 8;
        int d = e & (DIM - 1);
        int c = d >> 6, w = d & (CW - 1);
        union { unsigned short us[8]; uint4 v; } o;
        o.us[0] = f2h(f0.x); o.us[1] = f2h(f0.y); o.us[2] = f2h(f0.z); o.us[3] = f2h(f0.w);
        o.us[4] = f2h(f1.x); o.us[5] = f2h(f1.y); o.us[6] = f2h(f1.z); o.us[7] = f2h(f1.w);
        *(uint4*)(tab16 + (size_t)(table * NCHUNK + c) * REGION_HALVES + row * CW + w) = o.v;
    }
    if (t < packn) {
        unsigned pk;
        if (t < B) {
            int h = trip[3 * (long)t], r = trip[3 * (long)t + 1], tt = trip[3 * (long)t + 2];
            unsigned oob = ((unsigned)h >= NROWS || (unsigned)r >= NROWS || (unsigned)tt >= NROWS)
                           ? (1u << 30) : 0u;
            unsigned hc = (unsigned)min(max(h, 0), NROWS - 1);
            unsigned rc = (unsigned)min(max(r, 0), NROWS - 1);
            unsigned tc = (unsigned)min(max(tt, 0), NROWS - 1);
            pk = hc | (rc << 10) | (tc << 20) | oob;
        } else pk = 1u << 31;
        packed[t] = pk;
    }
}

// ---- main: R5 math, 512-thread blocks, 2 independent barrier domains per CU ----
// 8 lanes/triplet, 128 B row-chunks. h,t from the single-buffered node chunk in
// LDS (wave ds_read_b128 = 8 rows x 128 B -> each bank exactly 8 words -> zero
// conflicts). r from the L2-resident global f16 table, 1-deep prefetch. 64.5 KB
// LDS + ~100 VGPR -> 2 blocks/CU (16 waves/CU, same as R5) but with DECOUPLED
// __syncthreads(): block B computes while block A drains its staging barrier.
__global__ __launch_bounds__(THREADS) void transe_main5(
    const unsigned short* __restrict__ tab16,
    const unsigned* __restrict__ packed,
    const int* __restrict__ trip,
    const float* __restrict__ node_f32,
    const float* __restrict__ rel_f32,
    float* __restrict__ out, int B)
{
    __shared__ __align__(16) unsigned short lbuf[REGION_HALVES];   // 64512 B

    const int tid  = threadIdx.x;
    const int wid  = tid >> 6;    // 0..7
    const int lane = tid & 63;
    const int g    = lane >> 3;   // group (triplet) within wave
    const int m    = lane & 7;    // member within group
    const int moff = m * 16;
    const int base = blockIdx.x * TPB;

    const char* srcb = (const char*)tab16;
    char* ldsb = (char*)lbuf;

    // stage node chunk 0 (async global->LDS, wave-uniform dest + lane*16)
    #pragma unroll 1
    for (int i = wid; i < STAGE_ITERS; i += WAVES) {
        __builtin_amdgcn_global_load_lds(
            (const __attribute__((address_space(1))) unsigned int*)
                (srcb + (size_t)i * 1024 + (size_t)lane * 16),
            (__attribute__((address_space(3))) unsigned int*)(ldsb + i * 1024),
            16, 0, 0);
    }

    // my 16 packed triplet words straight from global (8-lane-uniform broadcasts)
    unsigned pidx[PASSES];
    #pragma unroll
    for (int p = 0; p < PASSES; ++p)
        pidx[p] = packed[base + wid * (8 * PASSES) + p * 8 + g];

    float acc[PASSES];
    #pragma unroll
    for (int p = 0; p < PASSES; ++p) acc[p] = 0.f;

    __syncthreads();   // chunk 0 staged

    for (int c = 0; c < NCHUNK; ++c) {
        const char* relc = srcb + (size_t)(NCHUNK + c) * REGION_BYTES;

        uint4 rnext = *(const uint4*)(relc + (((pidx[0] >> 10) & 1023u) << 7) + moff);
        #pragma unroll
        for (int p = 0; p < PASSES; ++p) {
            uint4 rv = rnext;
            if (p + 1 < PASSES)
                rnext = *(const uint4*)(relc + (((pidx[p + 1] >> 10) & 1023u) << 7) + moff);
            unsigned pk = pidx[p];
            uint4 hv = *(const uint4*)(ldsb + ((pk & 1023u) << 7) + moff);
            uint4 tv = *(const uint4*)(ldsb + (((pk >> 20) & 1023u) << 7) + moff);
            float a0 = acc[p], a1 = 0.f;
            a0 = acc_pair(hv.x, rv.x, tv.x, a0);
            a1 = acc_pair(hv.y, rv.y, tv.y, a1);
            a0 = acc_pair(hv.z, rv.z, tv.z, a0);
            a1 = acc_pair(hv.w, rv.w, tv.w, a1);
            acc[p] = a0 + a1;
        }

        if (c + 1 < NCHUNK) {
            __syncthreads();   // all waves of THIS block done reading chunk c
            const char* cb = srcb + (size_t)(c + 1) * REGION_BYTES;
            #pragma unroll 1
            for (int i = wid; i < STAGE_ITERS; i += WAVES) {
                __builtin_amdgcn_global_load_lds(
                    (const __attribute__((address_space(1))) unsigned int*)
                        (cb + (size_t)i * 1024 + (size_t)lane * 16),
                    (__attribute__((address_space(3))) unsigned int*)(ldsb + i * 1024),
                    16, 0, 0);
            }
            __syncthreads();   // chunk c+1 staged (other block computes meanwhile)
        }
    }

    // reduce over the 8 members of each group; member 0 writes
    #pragma unroll
    for (int p = 0; p < PASSES; ++p) {
        float a = acc[p];
        a += __shfl_xor(a, 1, 64);
        a += __shfl_xor(a, 2, 64);
        a += __shfl_xor(a, 4, 64);
        if (m == 0) {
            unsigned pk = pidx[p];
            long j = base + wid * (8 * PASSES) + p * 8 + g;
            if (!(pk >> 30)) {
                out[j] = GAMMA - a;
            } else if (!(pk >> 31)) {   // oob index: exact f32 fallback (never hit here)
                int hh = trip[3 * j], rr = trip[3 * j + 1], tt = trip[3 * j + 2];
                float s = 0.f;
                for (int d = 0; d < DIM; ++d)
                    s += fabsf(node_f32[(size_t)hh * DIM + d] + rel_f32[(size_t)rr * DIM + d]
                             - node_f32[(size_t)tt * DIM + d]);
                out[j] = GAMMA - s;
            }
        }
    }
}

// Fallback (only if ws is too small)
__global__ __launch_bounds__(256) void transe_direct(
    const float* __restrict__ node_emb,
    const float* __restrict__ rel_emb,
    const int*   __restrict__ triplets,
    float*       __restrict__ out, int B)
{
    const int wave = blockIdx.x * (blockDim.x >> 6) + (threadIdx.x >> 6);
    const int lane = threadIdx.x & 63;
    if (wave >= B) return;
    const int h_idx = triplets[wave * 3 + 0];
    const int r_idx = triplets[wave * 3 + 1];
    const int t_idx = triplets[wave * 3 + 2];
    const float4 h = ((const float4*)(node_emb + (size_t)h_idx * DIM))[lane];
    const float4 r = ((const float4*)(rel_emb  + (size_t)r_idx * DIM))[lane];
    const float4 t = ((const float4*)(node_emb + (size_t)t_idx * DIM))[lane];
    float s = fabsf(h.x + r.x - t.x) + fabsf(h.y + r.y - t.y)
            + fabsf(h.z + r.z - t.z) + fabsf(h.w + r.w - t.w);
    #pragma unroll
    for (int off = 32; off > 0; off >>= 1) s += __shfl_down(s, off, 64);
    if (lane == 0) out[wave] = GAMMA - s;
}

extern "C" void kernel_launch(void* const* d_in, const int* in_sizes, int n_in,
                              void* d_out, int out_size, void* d_ws, size_t ws_size,
                              hipStream_t stream) {
    const float* node_emb = (const float*)d_in[0];
    const float* rel_emb  = (const float*)d_in[1];
    const int*   triplets = (const int*)d_in[2];
    float*       out      = (float*)d_out;
    const int B = out_size;

    const int grid  = (B + TPB - 1) / TPB;   // 489 blocks -> ~2 per CU
    const int packn = grid * TPB;
    const size_t ws_needed = TAB_BYTES + (size_t)packn * 4;

    if (ws_size < ws_needed) {
        transe_direct<<<(B + 3) / 4, 256, 0, stream>>>(node_emb, rel_emb, triplets, out, B);
        return;
    }

    unsigned short* tab16 = (unsigned short*)d_ws;
    unsigned* packed = (unsigned*)((char*)d_ws + TAB_BYTES);

    const int prep_threads = (2 * NROWS * DIM / 8 > packn) ? (2 * NROWS * DIM / 8) : packn;
    transe_prep<<<(prep_threads + 255) / 256, 256, 0, stream>>>(
        node_emb, rel_emb, triplets, tab16, packed, B, packn);

    transe_main5<<<grid, THREADS, 0, stream>>>(
        tab16, packed, triplets, node_emb, rel_emb, out, B);
}

// Round 12
// 31.316 us; speedup vs baseline: 5.8962x; 1.9725x over previous
//
#include <hip/hip_runtime.h>

#define GAMMA 12.0f
#define DIM 256
#define NROWS 500
#define CW 128                              // halves per chunk slice (256 B rows)
#define NCHUNK 2                            // DIM / CW
#define ROWS_PAD 504                        // region = 504*256 B = 129024 B
#define REGION_HALVES (ROWS_PAD * CW)       // 64512
#define REGION_BYTES (REGION_HALVES * 2)    // 129024
#define STAGE_ITERS (REGION_BYTES / 1024)   // 126 wave-loads of 1024 B per chunk
#define THREADS 1024
#define WAVES 16
#define PASSES 16                           // 2048 triplets / (16 waves * 8 groups)
#define TPB 2048
#define TAB_BYTES ((size_t)2 * NCHUNK * REGION_HALVES * 2)   // 516096

typedef _Float16 h2 __attribute__((ext_vector_type(2)));

static __device__ __forceinline__ unsigned short f2h(float x) {
    _Float16 h = (_Float16)x;
    return __builtin_bit_cast(unsigned short, h);
}

// acc += |h + r - t| over one packed f16 pair, f32 accumulate via v_dot2_f32_f16
static __device__ __forceinline__ float acc_pair(unsigned uh, unsigned ur, unsigned ut, float acc) {
    h2 h = __builtin_bit_cast(h2, uh);
    h2 r = __builtin_bit_cast(h2, ur);
    h2 t = __builtin_bit_cast(h2, ut);
    h2 d = (h + r) - t;                                           // v_pk_add_f16 x2
    unsigned ad = __builtin_bit_cast(unsigned, d) & 0x7FFF7FFFu;  // packed abs
    h2 one = { (_Float16)1.0f, (_Float16)1.0f };
    return __builtin_amdgcn_fdot2(__builtin_bit_cast(h2, ad), one, acc, false);
}

// ---- prep: f16 tables (chunk-major, 256 B rows) + packed triplet words ----
// tab16: [table][chunk][ROWS_PAD][CW] halves. packed: h|r<<10|t<<20|oob<<30|inv<<31
__global__ __launch_bounds__(256) void transe_prep(
    const float* __restrict__ node, const float* __restrict__ rel,
    const int* __restrict__ trip,
    unsigned short* __restrict__ tab16, unsigned* __restrict__ packed,
    int B, int packn)
{
    int t = blockIdx.x * 256 + threadIdx.x;
    const int per = NROWS * DIM;                 // 128000
    if (t < 2 * per / 8) {
        int t8 = t * 8;
        int table = t8 >= per;
        int e = t8 - table * per;
        const float* src = table ? rel : node;
        float4 f0 = *(const float4*)(src + e);
        float4 f1 = *(const float4*)(src + e + 4);
        int row = e >> 8;
        int d = e & (DIM - 1);
        int c = d >> 7, w = d & (CW - 1);        // w multiple of 8 -> 16B aligned store
        union { unsigned short us[8]; uint4 v; } o;
        o.us[0] = f2h(f0.x); o.us[1] = f2h(f0.y); o.us[2] = f2h(f0.z); o.us[3] = f2h(f0.w);
        o.us[4] = f2h(f1.x); o.us[5] = f2h(f1.y); o.us[6] = f2h(f1.z); o.us[7] = f2h(f1.w);
        *(uint4*)(tab16 + (size_t)(table * NCHUNK + c) * REGION_HALVES + row * CW + w) = o.v;
    }
    if (t < packn) {
        unsigned pk;
        if (t < B) {
            int h = trip[3 * (long)t], r = trip[3 * (long)t + 1], tt = trip[3 * (long)t + 2];
            unsigned oob = ((unsigned)h >= NROWS || (unsigned)r >= NROWS || (unsigned)tt >= NROWS)
                           ? (1u << 30) : 0u;
            unsigned hc = (unsigned)min(max(h, 0), NROWS - 1);
            unsigned rc = (unsigned)min(max(r, 0), NROWS - 1);
            unsigned tc = (unsigned)min(max(tt, 0), NROWS - 1);
            pk = hc | (rc << 10) | (tc << 20) | oob;
        } else pk = 1u << 31;
        packed[t] = pk;
    }
}

// ---- main: R5 skeleton, 2 chunks of 256 B rows -> 3 barriers, 1 restage ----
// 8 lanes/triplet. Per stream per pass: 2x b128 covering a 256 B row slice.
// Wave-wide ds_read_b128 puts exactly 8 words on every bank (the 1024 B/instr
// data-path floor) -> zero conflict inflation. h,t from the single-buffered
// node chunk in LDS; r from the L2-resident global f16 table, 1-deep prefetch.
__global__ __launch_bounds__(THREADS) void transe_main6(
    const unsigned short* __restrict__ tab16,
    const unsigned* __restrict__ packed,
    const int* __restrict__ trip,
    const float* __restrict__ node_f32,
    const float* __restrict__ rel_f32,
    float* __restrict__ out, int B)
{
    __shared__ __align__(16) unsigned short lbuf[REGION_HALVES];   // 129024 B

    const int tid  = threadIdx.x;
    const int wid  = tid >> 6;
    const int lane = tid & 63;
    const int g    = lane >> 3;   // group (triplet) within wave
    const int m    = lane & 7;    // member within group
    const int moff = m * 16;
    const int base = blockIdx.x * TPB;

    const char* srcb = (const char*)tab16;
    char* ldsb = (char*)lbuf;

    // stage node chunk 0 (async global->LDS, wave-uniform dest + lane*16)
    #pragma unroll 1
    for (int i = wid; i < STAGE_ITERS; i += WAVES) {
        __builtin_amdgcn_global_load_lds(
            (const __attribute__((address_space(1))) unsigned int*)
                (srcb + (size_t)i * 1024 + (size_t)lane * 16),
            (__attribute__((address_space(3))) unsigned int*)(ldsb + i * 1024),
            16, 0, 0);
    }

    // my 16 packed triplet words straight from global (8-lane-uniform broadcasts)
    unsigned pidx[PASSES];
    #pragma unroll
    for (int p = 0; p < PASSES; ++p)
        pidx[p] = packed[base + wid * (8 * PASSES) + p * 8 + g];

    float acc[PASSES];
    #pragma unroll
    for (int p = 0; p < PASSES; ++p) acc[p] = 0.f;

    __syncthreads();   // chunk 0 staged

    for (int c = 0; c < NCHUNK; ++c) {
        const char* relc = srcb + (size_t)(NCHUNK + c) * REGION_BYTES;

        unsigned rb0 = ((pidx[0] >> 10) & 1023u) << 8;
        uint4 rn0 = *(const uint4*)(relc + rb0 + moff);
        uint4 rn1 = *(const uint4*)(relc + rb0 + 128 + moff);

        #pragma unroll
        for (int p = 0; p < PASSES; ++p) {
            uint4 rv0 = rn0, rv1 = rn1;
            if (p + 1 < PASSES) {
                unsigned rbn = ((pidx[p + 1] >> 10) & 1023u) << 8;
                rn0 = *(const uint4*)(relc + rbn + moff);
                rn1 = *(const uint4*)(relc + rbn + 128 + moff);
            }
            unsigned pk = pidx[p];
            const char* hrow = ldsb + ((pk & 1023u) << 8) + moff;
            const char* trow = ldsb + (((pk >> 20) & 1023u) << 8) + moff;
            uint4 hv0 = *(const uint4*)(hrow);
            uint4 tv0 = *(const uint4*)(trow);
            uint4 hv1 = *(const uint4*)(hrow + 128);
            uint4 tv1 = *(const uint4*)(trow + 128);
            float a0 = acc[p], a1 = 0.f;
            a0 = acc_pair(hv0.x, rv0.x, tv0.x, a0);
            a1 = acc_pair(hv0.y, rv0.y, tv0.y, a1);
            a0 = acc_pair(hv0.z, rv0.z, tv0.z, a0);
            a1 = acc_pair(hv0.w, rv0.w, tv0.w, a1);
            a0 = acc_pair(hv1.x, rv1.x, tv1.x, a0);
            a1 = acc_pair(hv1.y, rv1.y, tv1.y, a1);
            a0 = acc_pair(hv1.z, rv1.z, tv1.z, a0);
            a1 = acc_pair(hv1.w, rv1.w, tv1.w, a1);
            acc[p] = a0 + a1;
        }

        if (c + 1 < NCHUNK) {
            __syncthreads();   // all waves done reading chunk c
            const char* cb = srcb + (size_t)(c + 1) * REGION_BYTES;
            #pragma unroll 1
            for (int i = wid; i < STAGE_ITERS; i += WAVES) {
                __builtin_amdgcn_global_load_lds(
                    (const __attribute__((address_space(1))) unsigned int*)
                        (cb + (size_t)i * 1024 + (size_t)lane * 16),
                    (__attribute__((address_space(3))) unsigned int*)(ldsb + i * 1024),
                    16, 0, 0);
            }
            __syncthreads();   // chunk c+1 staged
        }
    }

    // reduce over the 8 members of each group; member 0 writes
    #pragma unroll
    for (int p = 0; p < PASSES; ++p) {
        float a = acc[p];
        a += __shfl_xor(a, 1, 64);
        a += __shfl_xor(a, 2, 64);
        a += __shfl_xor(a, 4, 64);
        if (m == 0) {
            unsigned pk = pidx[p];
            long j = base + wid * (8 * PASSES) + p * 8 + g;
            if (!(pk >> 30)) {
                out[j] = GAMMA - a;
            } else if (!(pk >> 31)) {   // oob index: exact f32 fallback (never hit here)
                int hh = trip[3 * j], rr = trip[3 * j + 1], tt = trip[3 * j + 2];
                float s = 0.f;
                for (int d = 0; d < DIM; ++d)
                    s += fabsf(node_f32[(size_t)hh * DIM + d] + rel_f32[(size_t)rr * DIM + d]
                             - node_f32[(size_t)tt * DIM + d]);
                out[j] = GAMMA - s;
            }
        }
    }
}

// Fallback (only if ws is too small)
__global__ __launch_bounds__(256) void transe_direct(
    const float* __restrict__ node_emb,
    const float* __restrict__ rel_emb,
    const int*   __restrict__ triplets,
    float*       __restrict__ out, int B)
{
    const int wave = blockIdx.x * (blockDim.x >> 6) + (threadIdx.x >> 6);
    const int lane = threadIdx.x & 63;
    if (wave >= B) return;
    const int h_idx = triplets[wave * 3 + 0];
    const int r_idx = triplets[wave * 3 + 1];
    const int t_idx = triplets[wave * 3 + 2];
    const float4 h = ((const float4*)(node_emb + (size_t)h_idx * DIM))[lane];
    const float4 r = ((const float4*)(rel_emb  + (size_t)r_idx * DIM))[lane];
    const float4 t = ((const float4*)(node_emb + (size_t)t_idx * DIM))[lane];
    float s = fabsf(h.x + r.x - t.x) + fabsf(h.y + r.y - t.y)
            + fabsf(h.z + r.z - t.z) + fabsf(h.w + r.w - t.w);
    #pragma unroll
    for (int off = 32; off > 0; off >>= 1) s += __shfl_down(s, off, 64);
    if (lane == 0) out[wave] = GAMMA - s;
}

extern "C" void kernel_launch(void* const* d_in, const int* in_sizes, int n_in,
                              void* d_out, int out_size, void* d_ws, size_t ws_size,
                              hipStream_t stream) {
    const float* node_emb = (const float*)d_in[0];
    const float* rel_emb  = (const float*)d_in[1];
    const int*   triplets = (const int*)d_in[2];
    float*       out      = (float*)d_out;
    const int B = out_size;

    const int grid  = (B + TPB - 1) / TPB;   // 245 blocks, ~1/CU
    const int packn = grid * TPB;
    const size_t ws_needed = TAB_BYTES + (size_t)packn * 4;

    if (ws_size < ws_needed) {
        transe_direct<<<(B + 3) / 4, 256, 0, stream>>>(node_emb, rel_emb, triplets, out, B);
        return;
    }

    unsigned short* tab16 = (unsigned short*)d_ws;
    unsigned* packed = (unsigned*)((char*)d_ws + TAB_BYTES);

    const int prep_threads = (2 * NROWS * DIM / 8 > packn) ? (2 * NROWS * DIM / 8) : packn;
    transe_prep<<<(prep_threads + 255) / 256, 256, 0, stream>>>(
        node_emb, rel_emb, triplets, tab16, packed, B, packn);

    transe_main6<<<grid, THREADS, 0, stream>>>(
        tab16, packed, triplets, node_emb, rel_emb, out, B);
}

// Round 13
// 28.674 us; speedup vs baseline: 6.4393x; 1.0921x over previous
//
#include <hip/hip_runtime.h>

#define GAMMA 12.0f
#define DIM 256
#define NROWS 500
#define CW 64                               // halves per chunk slice (128 B rows)
#define NCHUNK 4                            // DIM / CW
#define ROWS_PAD 504                        // region = 504*128 B = 64512 B
#define REGION_HALVES (ROWS_PAD * CW)       // 32256
#define REGION_BYTES (REGION_HALVES * 2)    // 64512
#define STAGE_ITERS (REGION_BYTES / 1024)   // 63 wave-loads of 1024 B per chunk
#define THREADS 1024
#define WAVES 16
#define PASSES 16
#define TPB 2048                            // triplets per block

typedef _Float16 h2 __attribute__((ext_vector_type(2)));

static __device__ __forceinline__ unsigned short f2h(float x) {
    _Float16 h = (_Float16)x;
    return __builtin_bit_cast(unsigned short, h);
}

// acc += |h + r - t| over one packed f16 pair, f32 accumulate via v_dot2_f32_f16
static __device__ __forceinline__ float acc_pair(unsigned uh, unsigned ur, unsigned ut, float acc) {
    h2 h = __builtin_bit_cast(h2, uh);
    h2 r = __builtin_bit_cast(h2, ur);
    h2 t = __builtin_bit_cast(h2, ut);
    h2 d = (h + r) - t;                                           // v_pk_add_f16 x2
    unsigned ad = __builtin_bit_cast(unsigned, d) & 0x7FFF7FFFu;  // packed abs
    h2 one = { (_Float16)1.0f, (_Float16)1.0f };
    return __builtin_amdgcn_fdot2(__builtin_bit_cast(h2, ad), one, acc, false);
}

// tab16 layout: [table][chunk][ROWS_PAD][CW] halves (rows >= NROWS junk, never read)
__global__ __launch_bounds__(256) void transe_convert(
    const float* __restrict__ node, const float* __restrict__ rel,
    unsigned short* __restrict__ out)
{
    const int per = NROWS * DIM;                 // 128000
    int t8 = (blockIdx.x * 256 + threadIdx.x) * 8;
    if (t8 >= 2 * per) return;
    int table = t8 >= per;
    int e = t8 - table * per;
    const float* src = table ? rel : node;
    float4 f0 = *(const float4*)(src + e);
    float4 f1 = *(const float4*)(src + e + 4);
    int row = e >> 8;
    int d = e & (DIM - 1);
    int c = d >> 6, w = d & (CW - 1);            // w multiple of 8 -> 16B aligned store
    union { unsigned short us[8]; uint4 v; } o;
    o.us[0] = f2h(f0.x); o.us[1] = f2h(f0.y); o.us[2] = f2h(f0.z); o.us[3] = f2h(f0.w);
    o.us[4] = f2h(f1.x); o.us[5] = f2h(f1.y); o.us[6] = f2h(f1.z); o.us[7] = f2h(f1.w);
    *(uint4*)(out + (size_t)(table * NCHUNK + c) * REGION_HALVES + row * CW + w) = o.v;
}

// 8 lanes per triplet, 128 B per row-chunk. h,t come from a double-buffered node
// region in LDS (wave ds_read_b128 = 8 rows x 128 B -> every bank hit exactly 8x,
// zero conflicts). r comes straight from the L2-resident global f16 table on the
// VMEM pipe (coalesced 128 B segments), overlapping the LDS port. Next node chunk
// is staged via global_load_lds into the other buffer while computing.
__global__ __launch_bounds__(THREADS) void transe_main(
    const unsigned short* __restrict__ tab16,
    const int* __restrict__ trip,
    const float* __restrict__ node_f32,
    const float* __restrict__ rel_f32,
    float* __restrict__ out, int B)
{
    __shared__ __align__(16) unsigned short lbuf[2 * REGION_HALVES]; // 129024 B
    __shared__ int ltrip[TPB];                                       // 8192 B packed

    const int tid  = threadIdx.x;
    const int wid  = tid >> 6;
    const int lane = tid & 63;
    const int g    = lane >> 3;   // group (triplet) within wave
    const int m    = lane & 7;    // member within group
    const int moff = m * 16;
    const long base = (long)blockIdx.x * TPB;

    const char* srcb = (const char*)tab16;
    char* ldsb = (char*)lbuf;

    // ---- issue chunk-0 node staging into buf0 (async global->LDS) ----
    #pragma unroll 1
    for (int i = wid; i < STAGE_ITERS; i += WAVES) {
        const char* src = srcb + (size_t)i * 1024 + (size_t)lane * 16;
        char* dst = ldsb + i * 1024;
        __builtin_amdgcn_global_load_lds(
            (const __attribute__((address_space(1))) unsigned int*)src,
            (__attribute__((address_space(3))) unsigned int*)dst, 16, 0, 0);
    }

    // ---- pack triplets: h | r<<10 | t<<20 | oob<<30 | invalid<<31 (clamped) ----
    for (int s = tid; s < TPB; s += THREADS) {
        long j = base + s;
        unsigned pk;
        if (j < B) {
            int h = trip[3 * j], r = trip[3 * j + 1], t = trip[3 * j + 2];
            unsigned oob = ((unsigned)h >= NROWS || (unsigned)r >= NROWS || (unsigned)t >= NROWS)
                           ? (1u << 30) : 0u;
            unsigned hc = (unsigned)min(max(h, 0), NROWS - 1);
            unsigned rc = (unsigned)min(max(r, 0), NROWS - 1);
            unsigned tc = (unsigned)min(max(t, 0), NROWS - 1);
            pk = hc | (rc << 10) | (tc << 20) | oob;
        } else pk = 1u << 31;
        ltrip[s] = (int)pk;
    }
    __syncthreads();   // ltrip ready AND chunk-0 staged

    unsigned pidx[PASSES];
    #pragma unroll
    for (int p = 0; p < PASSES; ++p)
        pidx[p] = (unsigned)ltrip[wid * (8 * PASSES) + p * 8 + g];

    float acc[PASSES];
    #pragma unroll
    for (int p = 0; p < PASSES; ++p) acc[p] = 0.f;

    for (int c = 0; c < NCHUNK; ++c) {
        // stage next node chunk into the other buffer (flies during compute)
        if (c + 1 < NCHUNK) {
            const char* cb = srcb + (size_t)(c + 1) * REGION_BYTES;
            char* db = ldsb + ((c + 1) & 1) * REGION_BYTES;
            #pragma unroll 1
            for (int i = wid; i < STAGE_ITERS; i += WAVES) {
                __builtin_amdgcn_global_load_lds(
                    (const __attribute__((address_space(1))) unsigned int*)
                        (cb + (size_t)i * 1024 + (size_t)lane * 16),
                    (__attribute__((address_space(3))) unsigned int*)(db + i * 1024),
                    16, 0, 0);
            }
        }

        const char* lbase = ldsb + (c & 1) * REGION_BYTES;
        const char* relc  = srcb + (size_t)(NCHUNK + c) * REGION_BYTES;

        uint4 rnext = *(const uint4*)(relc + (((pidx[0] >> 10) & 1023u) << 7) + moff);
        #pragma unroll
        for (int p = 0; p < PASSES; ++p) {
            uint4 rv = rnext;
            if (p + 1 < PASSES)
                rnext = *(const uint4*)(relc + (((pidx[p + 1] >> 10) & 1023u) << 7) + moff);
            unsigned pk = pidx[p];
            uint4 hv = *(const uint4*)(lbase + ((pk & 1023u) << 7) + moff);
            uint4 tv = *(const uint4*)(lbase + (((pk >> 20) & 1023u) << 7) + moff);
            float a = acc[p];
            a = acc_pair(hv.x, rv.x, tv.x, a);
            a = acc_pair(hv.y, rv.y, tv.y, a);
            a = acc_pair(hv.z, rv.z, tv.z, a);
            a = acc_pair(hv.w, rv.w, tv.w, a);
            acc[p] = a;
        }

        __syncthreads();  // all waves done reading buf[c&1]; stage(c+1) drained pre-barrier
    }

    // reduce over the 8 members of each group; member 0 writes
    #pragma unroll
    for (int p = 0; p < PASSES; ++p) {
        float a = acc[p];
        a += __shfl_xor(a, 1, 64);
        a += __shfl_xor(a, 2, 64);
        a += __shfl_xor(a, 4, 64);
        if (m == 0) {
            unsigned pk = pidx[p];
            int slot = wid * (8 * PASSES) + p * 8 + g;
            long j = base + slot;
            if (!(pk >> 30)) {
                out[j] = GAMMA - a;
            } else if (!(pk >> 31)) {   // oob index: exact f32 fallback (never hit here)
                int hh = trip[3 * j], rr = trip[3 * j + 1], tt = trip[3 * j + 2];
                float s = 0.f;
                for (int d = 0; d < DIM; ++d)
                    s += fabsf(node_f32[(size_t)hh * DIM + d] + rel_f32[(size_t)rr * DIM + d]
                             - node_f32[(size_t)tt * DIM + d]);
                out[j] = GAMMA - s;
            }
        }
    }
}

// Round-1 fallback (only if d_ws is too small for the f16 tables)
__global__ __launch_bounds__(256) void transe_direct(
    const float* __restrict__ node_emb,
    const float* __restrict__ rel_emb,
    const int*   __restrict__ triplets,
    float*       __restrict__ out, int B)
{
    const int wave = blockIdx.x * (blockDim.x >> 6) + (threadIdx.x >> 6);
    const int lane = threadIdx.x & 63;
    if (wave >= B) return;
    const int h_idx = triplets[wave * 3 + 0];
    const int r_idx = triplets[wave * 3 + 1];
    const int t_idx = triplets[wave * 3 + 2];
    const float4 h = ((const float4*)(node_emb + (size_t)h_idx * DIM))[lane];
    const float4 r = ((const float4*)(rel_emb  + (size_t)r_idx * DIM))[lane];
    const float4 t = ((const float4*)(node_emb + (size_t)t_idx * DIM))[lane];
    float s = fabsf(h.x + r.x - t.x) + fabsf(h.y + r.y - t.y)
            + fabsf(h.z + r.z - t.z) + fabsf(h.w + r.w - t.w);
    #pragma unroll
    for (int off = 32; off > 0; off >>= 1) s += __shfl_down(s, off, 64);
    if (lane == 0) out[wave] = GAMMA - s;
}

extern "C" void kernel_launch(void* const* d_in, const int* in_sizes, int n_in,
                              void* d_out, int out_size, void* d_ws, size_t ws_size,
                              hipStream_t stream) {
    const float* node_emb = (const float*)d_in[0];
    const float* rel_emb  = (const float*)d_in[1];
    const int*   triplets = (const int*)d_in[2];
    float*       out      = (float*)d_out;
    const int B = out_size;

    const size_t ws_needed = (size_t)2 * NCHUNK * REGION_HALVES * sizeof(unsigned short); // 516096
    if (ws_size < ws_needed) {
        const int grid = (B + 3) / 4;
        transe_direct<<<grid, 256, 0, stream>>>(node_emb, rel_emb, triplets, out, B);
        return;
    }

    unsigned short* tab16 = (unsigned short*)d_ws;

    const int conv_threads = 2 * NROWS * DIM / 8;   // 32000
    transe_convert<<<(conv_threads + 255) / 256, 256, 0, stream>>>(node_emb, rel_emb, tab16);

    const int grid = (B + TPB - 1) / TPB;           // 245 blocks, 1/CU
    transe_main<<<grid, THREADS, 0, stream>>>(tab16, triplets, node_emb, rel_emb, out, B);
}